// Round 5
// baseline (476.203 us; speedup 1.0000x reference)
//
#include <hip/hip_runtime.h>
#include <hip/hip_bf16.h>

typedef __attribute__((ext_vector_type(4))) float f32x4;
typedef __attribute__((ext_vector_type(8))) __bf16 bf16x8;
typedef __attribute__((ext_vector_type(4))) __bf16 bf16x4;
typedef unsigned long long u64;

#define DIMQ 512
#define NSEQ 4096
#define NHEAD 16
#define HDIM 32
#define SCALE_QK 0.17677669529663687f

__device__ __forceinline__ void gload16(void* lds, const void* g) {
  __builtin_amdgcn_global_load_lds(
      (const __attribute__((address_space(1))) void*)g,
      (__attribute__((address_space(3))) void*)lds, 16, 0, 0);
}

// ---------------- conversion kernels ----------------

__global__ __launch_bounds__(256) void k_cvt_bf16(const float* __restrict__ in,
                                                  __bf16* __restrict__ out) {
  int i = blockIdx.x * 256 + threadIdx.x;
  float4 v = reinterpret_cast<const float4*>(in)[i];
  bf16x4 o;
  o.x = (__bf16)v.x; o.y = (__bf16)v.y; o.z = (__bf16)v.z; o.w = (__bf16)v.w;
  reinterpret_cast<bf16x4*>(out)[i] = o;
}

// in: fp32 [512][Nc]  ->  out: bf16 [Nc][512]  (transpose via LDS tile)
__global__ __launch_bounds__(256) void k_cvtT(const float* __restrict__ in,
                                              __bf16* __restrict__ out, int Nc) {
  __shared__ __bf16 t[64][72];
  int k0 = blockIdx.y * 64, n0 = blockIdx.x * 64;
  int c = threadIdx.x & 63, rr = threadIdx.x >> 6;
#pragma unroll
  for (int i = 0; i < 16; ++i) {
    int r = rr * 16 + i;
    t[r][c] = (__bf16)in[(size_t)(k0 + r) * Nc + n0 + c];
  }
  __syncthreads();
#pragma unroll
  for (int i = 0; i < 16; ++i) {
    int r = rr * 16 + i;
    out[(size_t)(n0 + r) * 512 + k0 + c] = t[c][r];
  }
}

// int32 mask [4096][4096] -> bit mask [4096][64] u64 (bit j of word w = mask[row][w*64+j])
__global__ __launch_bounds__(256) void k_maskbits(const int* __restrict__ mask,
                                                  u64* __restrict__ bits) {
  int row = blockIdx.x;
  int l = threadIdx.x & 63, w = threadIdx.x >> 6;
  const int* mr = mask + (size_t)row * NSEQ;
  for (int t = w; t < 64; t += 4) {
    u64 b = __ballot(mr[t * 64 + l] != 0);
    if (l == 0) bits[(size_t)row * 64 + t] = b;
  }
}

// ---------------- shared GEMM main loop (m97-style, swizzled gload_lds) ----------------
__device__ __forceinline__ void gemm_mainloop(const __bf16* __restrict__ A,
                                              const __bf16* __restrict__ Bt,
                                              int m0, int n0,
                                              __bf16* As, __bf16* Bs,
                                              f32x4 acc[4][4]) {
  const int tid = threadIdx.x, l = tid & 63, w = tid >> 6;
  const int wr = w >> 1, wc = w & 1;
  for (int kt = 0; kt < DIMQ; kt += 64) {
    __syncthreads();
#pragma unroll
    for (int it = 0; it < 4; ++it) {
      int c = it * 256 + tid;
      int row = c >> 3, j = c & 7, js = j ^ (row & 7);
      gload16(As + (size_t)(it * 256 + w * 64) * 8,
              A + (size_t)(m0 + row) * DIMQ + kt + js * 8);
      gload16(Bs + (size_t)(it * 256 + w * 64) * 8,
              Bt + (size_t)(n0 + row) * DIMQ + kt + js * 8);
    }
    __syncthreads();
#pragma unroll
    for (int kk = 0; kk < 2; ++kk) {
      bf16x8 a[4], b[4];
#pragma unroll
      for (int mt = 0; mt < 4; ++mt) {
        int row = wr * 64 + mt * 16 + (l & 15);
        int g = (kk * 4 + (l >> 4)) ^ (row & 7);
        a[mt] = *reinterpret_cast<const bf16x8*>((const char*)As + row * 128 + g * 16);
      }
#pragma unroll
      for (int nt = 0; nt < 4; ++nt) {
        int row = wc * 64 + nt * 16 + (l & 15);
        int g = (kk * 4 + (l >> 4)) ^ (row & 7);
        b[nt] = *reinterpret_cast<const bf16x8*>((const char*)Bs + row * 128 + g * 16);
      }
#pragma unroll
      for (int mt = 0; mt < 4; ++mt)
#pragma unroll
        for (int nt = 0; nt < 4; ++nt)
          acc[mt][nt] = __builtin_amdgcn_mfma_f32_16x16x32_bf16(a[mt], b[nt], acc[mt][nt], 0, 0, 0);
    }
  }
}

// ---------------- QKV GEMM (epilogue scatters to head layout, V transposed) ----------------
__global__ __launch_bounds__(256) void k_gemm_qkv(const __bf16* __restrict__ A,
                                                  const __bf16* __restrict__ Bt,
                                                  __bf16* __restrict__ Qh,
                                                  __bf16* __restrict__ Kh,
                                                  __bf16* __restrict__ VT) {
  __shared__ __bf16 As[128 * 64], Bs[128 * 64];
  f32x4 acc[4][4] = {};
  const int l = threadIdx.x & 63, w = threadIdx.x >> 6, wr = w >> 1, wc = w & 1;
  const int m0 = blockIdx.y * 128, n0 = blockIdx.x * 128;
  gemm_mainloop(A, Bt, m0, n0, As, Bs, acc);
#pragma unroll
  for (int nt = 0; nt < 4; ++nt) {
    int n = n0 + wc * 64 + nt * 16 + (l & 15);
    int sec = n >> 9;           // 0=q 1=k 2=v
    int hh = (n >> 5) & 15;     // head
    int d = n & 31;             // dim in head
#pragma unroll
    for (int mt = 0; mt < 4; ++mt) {
      int m = m0 + wr * 64 + mt * 16 + (l >> 4) * 4;
      int bb = m >> 12, nn = m & 4095;
      size_t bh = (size_t)bb * NHEAD + hh;
      f32x4 v = acc[mt][nt];
      if (sec == 0) {
        __bf16* p = Qh + (bh * NSEQ + nn) * HDIM + d;
        p[0] = (__bf16)v[0]; p[HDIM] = (__bf16)v[1];
        p[2 * HDIM] = (__bf16)v[2]; p[3 * HDIM] = (__bf16)v[3];
      } else if (sec == 1) {
        __bf16* p = Kh + (bh * NSEQ + nn) * HDIM + d;
        p[0] = (__bf16)v[0]; p[HDIM] = (__bf16)v[1];
        p[2 * HDIM] = (__bf16)v[2]; p[3 * HDIM] = (__bf16)v[3];
      } else {
        bf16x4 o;
        o.x = (__bf16)v[0]; o.y = (__bf16)v[1]; o.z = (__bf16)v[2]; o.w = (__bf16)v[3];
        *reinterpret_cast<bf16x4*>(VT + (bh * HDIM + d) * NSEQ + nn) = o;
      }
    }
  }
}

// ---------------- fused masked attention, v2 ----------------
// grid (32 q-tiles, 32 bh), 256 thr. Wave w owns 32 q rows. KV tile = 64.
// Swapped QK^T (S^T in regs, q = lane&15), no-max softmax (statically safe),
// k-permuted PV (P stays lane-local; V loaded with matching permuted addrs).
// No LDS, no barriers, all loads direct from global (L2-resident).
__global__ __launch_bounds__(256) void k_attn(const __bf16* __restrict__ Qh,
                                              const __bf16* __restrict__ Kh,
                                              const __bf16* __restrict__ VT,
                                              const u64* __restrict__ mbits,
                                              __bf16* __restrict__ O) {
  const int l = threadIdx.x & 63, w = threadIdx.x >> 6;
  const int g = l >> 4, q16 = l & 15;
  const int bh = blockIdx.y;
  const int q0 = blockIdx.x * 128 + w * 32;
  const __bf16* Qb = Qh + (size_t)bh * NSEQ * HDIM;
  const __bf16* Kb = Kh + (size_t)bh * NSEQ * HDIM;
  const __bf16* Vb = VT + (size_t)bh * HDIM * NSEQ;  // [32][4096]

  bf16x8 qf[2];
#pragma unroll
  for (int rt = 0; rt < 2; ++rt)
    qf[rt] = *reinterpret_cast<const bf16x8*>(
        Qb + (size_t)(q0 + rt * 16 + q16) * HDIM + g * 8);

  f32x4 acc[2][2] = {};
  float lsum[2] = {0.f, 0.f};
  const float C2 = SCALE_QK * 1.4426950408889634f;  // fold log2(e) into scale

  for (int kv = 0; kv < NSEQ / 64; ++kv) {
    // K fragments: A-operand of S^T = K rows, coalesced 1KB/instruction
    bf16x8 kf[4];
#pragma unroll
    for (int f = 0; f < 4; ++f)
      kf[f] = *reinterpret_cast<const bf16x8*>(
          Kb + (size_t)(kv * 64 + f * 16 + q16) * HDIM + g * 8);

    // V fragments with permuted-k layout: slot (g,e) holds V[jj*32+16*(e>>2)+4g+(e&3)][d]
    bf16x4 vlo[2][2], vhi[2][2];
#pragma unroll
    for (int jj = 0; jj < 2; ++jj)
#pragma unroll
      for (int dt = 0; dt < 2; ++dt) {
        const __bf16* vr =
            Vb + (size_t)(dt * 16 + q16) * NSEQ + kv * 64 + jj * 32 + g * 4;
        vlo[jj][dt] = *reinterpret_cast<const bf16x4*>(vr);
        vhi[jj][dt] = *reinterpret_cast<const bf16x4*>(vr + 16);
      }

    const u64 mw0 = mbits[(size_t)(q0 + q16) * 64 + kv];
    const u64 mw1 = mbits[(size_t)(q0 + 16 + q16) * 64 + kv];

#pragma unroll
    for (int rt = 0; rt < 2; ++rt) {
      const u64 mw = rt ? mw1 : mw0;
      const f32x4 z = {0.f, 0.f, 0.f, 0.f};
      f32x4 s[4];
#pragma unroll
      for (int f = 0; f < 4; ++f)  // S^T tile: lane holds q=q0+rt*16+q16, k=16f+4g+r
        s[f] = __builtin_amdgcn_mfma_f32_16x16x32_bf16(kf[f], qf[rt], z, 0, 0, 0);

      float p[4][4];
      float ls = 0.f;
#pragma unroll
      for (int f = 0; f < 4; ++f)
#pragma unroll
        for (int r = 0; r < 4; ++r) {
          float pv = __builtin_exp2f(s[f][r] * C2);
          pv = ((mw >> (f * 16 + g * 4 + r)) & 1) ? pv : 0.f;
          p[f][r] = pv;
          ls += pv;
        }
      lsum[rt] += ls;

#pragma unroll
      for (int jj = 0; jj < 2; ++jj) {
        bf16x8 pa;  // natural per-lane k order (matches permuted V)
#pragma unroll
        for (int r = 0; r < 4; ++r) {
          pa[r] = (__bf16)p[2 * jj][r];
          pa[r + 4] = (__bf16)p[2 * jj + 1][r];
        }
#pragma unroll
        for (int dt = 0; dt < 2; ++dt) {
          bf16x8 vb;
#pragma unroll
          for (int e = 0; e < 4; ++e) {
            vb[e] = vlo[jj][dt][e];
            vb[e + 4] = vhi[jj][dt][e];
          }
          acc[rt][dt] =
              __builtin_amdgcn_mfma_f32_16x16x32_bf16(pa, vb, acc[rt][dt], 0, 0, 0);
        }
      }
    }
  }

#pragma unroll
  for (int rt = 0; rt < 2; ++rt) {
    lsum[rt] += __shfl_xor(lsum[rt], 16);
    lsum[rt] += __shfl_xor(lsum[rt], 32);
  }

  const int bb = bh >> 4, hh = bh & 15;
#pragma unroll
  for (int rt = 0; rt < 2; ++rt)
#pragma unroll
    for (int r = 0; r < 4; ++r) {
      float inv = 1.f / __shfl(lsum[rt], g * 4 + r);  // row-sum lives at lane q16==g*4+r
      int qrow = q0 + rt * 16 + g * 4 + r;
#pragma unroll
      for (int dt = 0; dt < 2; ++dt)
        O[((size_t)bb * NSEQ + qrow) * DIMQ + hh * HDIM + dt * 16 + q16] =
            (__bf16)(acc[rt][dt][r] * inv);
    }
}

// ---------------- output projection GEMM (fp32 output) ----------------
__global__ __launch_bounds__(256) void k_gemm_proj(const __bf16* __restrict__ A,
                                                   const __bf16* __restrict__ Bt,
                                                   float* __restrict__ Out) {
  __shared__ __bf16 As[128 * 64], Bs[128 * 64];
  f32x4 acc[4][4] = {};
  const int l = threadIdx.x & 63, w = threadIdx.x >> 6, wr = w >> 1, wc = w & 1;
  const int m0 = blockIdx.y * 128, n0 = blockIdx.x * 128;
  gemm_mainloop(A, Bt, m0, n0, As, Bs, acc);
#pragma unroll
  for (int nt = 0; nt < 4; ++nt) {
    int n = n0 + wc * 64 + nt * 16 + (l & 15);
#pragma unroll
    for (int mt = 0; mt < 4; ++mt) {
      int m = m0 + wr * 64 + mt * 16 + (l >> 4) * 4;
      f32x4 v = acc[mt][nt];
      float* p = Out + (size_t)m * DIMQ + n;
      p[0] = v[0]; p[DIMQ] = v[1];
      p[2 * DIMQ] = v[2]; p[3 * DIMQ] = v[3];
    }
  }
}

// ---------------- launcher ----------------
extern "C" void kernel_launch(void* const* d_in, const int* in_sizes, int n_in,
                              void* d_out, int out_size, void* d_ws, size_t ws_size,
                              hipStream_t stream) {
  (void)in_sizes; (void)n_in; (void)out_size; (void)ws_size;
  const float* batch  = (const float*)d_in[0];
  const float* w_qkv  = (const float*)d_in[1];
  const float* w_proj = (const float*)d_in[2];
  const int*   cmask  = (const int*)d_in[3];

  __bf16* Abf = (__bf16*)d_ws;                       // 8192*512 bf16
  __bf16* WqT = Abf + (size_t)8192 * 512;            // 1536*512
  __bf16* WpT = WqT + (size_t)1536 * 512;            // 512*512
  u64*    mb  = (u64*)(WpT + (size_t)512 * 512);     // 4096*64 u64
  __bf16* Qh  = (__bf16*)(mb + (size_t)4096 * 64);   // 32*4096*32
  __bf16* Kh  = Qh + (size_t)32 * NSEQ * HDIM;
  __bf16* VT  = Kh + (size_t)32 * NSEQ * HDIM;
  __bf16* Obf = VT + (size_t)32 * NSEQ * HDIM;       // 8192*512

  k_cvt_bf16<<<4096, 256, 0, stream>>>(batch, Abf);
  k_cvtT<<<dim3(24, 8), 256, 0, stream>>>(w_qkv, WqT, 1536);
  k_cvtT<<<dim3(8, 8), 256, 0, stream>>>(w_proj, WpT, 512);
  k_maskbits<<<4096, 256, 0, stream>>>(cmask, mb);
  k_gemm_qkv<<<dim3(12, 64), 256, 0, stream>>>(Abf, WqT, Qh, Kh, VT);
  k_attn<<<dim3(32, 32), 256, 0, stream>>>(Qh, Kh, VT, mb, Obf);
  k_gemm_proj<<<dim3(4, 64), 256, 0, stream>>>(Obf, WpT, (float*)d_out);
}

// Round 6
// 436.190 us; speedup vs baseline: 1.0917x; 1.0917x over previous
//
#include <hip/hip_runtime.h>
#include <hip/hip_bf16.h>

typedef __attribute__((ext_vector_type(4))) float f32x4;
typedef __attribute__((ext_vector_type(8))) __bf16 bf16x8;
typedef __attribute__((ext_vector_type(4))) __bf16 bf16x4;
typedef unsigned long long u64;

#define DIMQ 512
#define NSEQ 4096
#define NHEAD 16
#define HDIM 32
#define SCALE_QK 0.17677669529663687f
#define C2F (SCALE_QK * 1.4426950408889634f)  // scale * log2(e), folded into Q

__device__ __forceinline__ void gload16(void* lds, const void* g) {
  __builtin_amdgcn_global_load_lds(
      (const __attribute__((address_space(1))) void*)g,
      (__attribute__((address_space(3))) void*)lds, 16, 0, 0);
}

// ---------------- conversion kernels ----------------

__global__ __launch_bounds__(256) void k_cvt_bf16(const float* __restrict__ in,
                                                  __bf16* __restrict__ out) {
  int i = blockIdx.x * 256 + threadIdx.x;
  float4 v = reinterpret_cast<const float4*>(in)[i];
  bf16x4 o;
  o.x = (__bf16)v.x; o.y = (__bf16)v.y; o.z = (__bf16)v.z; o.w = (__bf16)v.w;
  reinterpret_cast<bf16x4*>(out)[i] = o;
}

// in: fp32 [512][Nc]  ->  out: bf16 [Nc][512]  (transpose via LDS tile)
__global__ __launch_bounds__(256) void k_cvtT(const float* __restrict__ in,
                                              __bf16* __restrict__ out, int Nc) {
  __shared__ __bf16 t[64][72];
  int k0 = blockIdx.y * 64, n0 = blockIdx.x * 64;
  int c = threadIdx.x & 63, rr = threadIdx.x >> 6;
#pragma unroll
  for (int i = 0; i < 16; ++i) {
    int r = rr * 16 + i;
    t[r][c] = (__bf16)in[(size_t)(k0 + r) * Nc + n0 + c];
  }
  __syncthreads();
#pragma unroll
  for (int i = 0; i < 16; ++i) {
    int r = rr * 16 + i;
    out[(size_t)(n0 + r) * 512 + k0 + c] = t[c][r];
  }
}

// int32 mask [4096][4096] -> bit mask [4096][64] u64 (bit j of word w = mask[row][w*64+j])
__global__ __launch_bounds__(256) void k_maskbits(const int* __restrict__ mask,
                                                  u64* __restrict__ bits) {
  int row = blockIdx.x;
  int l = threadIdx.x & 63, w = threadIdx.x >> 6;
  const int* mr = mask + (size_t)row * NSEQ;
  for (int t = w; t < 64; t += 4) {
    u64 b = __ballot(mr[t * 64 + l] != 0);
    if (l == 0) bits[(size_t)row * 64 + t] = b;
  }
}

// ---------------- shared GEMM main loop (m97-style, swizzled gload_lds) ----------------
__device__ __forceinline__ void gemm_mainloop(const __bf16* __restrict__ A,
                                              const __bf16* __restrict__ Bt,
                                              int m0, int n0,
                                              __bf16* As, __bf16* Bs,
                                              f32x4 acc[4][4]) {
  const int tid = threadIdx.x, l = tid & 63, w = tid >> 6;
  const int wr = w >> 1, wc = w & 1;
  for (int kt = 0; kt < DIMQ; kt += 64) {
    __syncthreads();
#pragma unroll
    for (int it = 0; it < 4; ++it) {
      int c = it * 256 + tid;
      int row = c >> 3, j = c & 7, js = j ^ (row & 7);
      gload16(As + (size_t)(it * 256 + w * 64) * 8,
              A + (size_t)(m0 + row) * DIMQ + kt + js * 8);
      gload16(Bs + (size_t)(it * 256 + w * 64) * 8,
              Bt + (size_t)(n0 + row) * DIMQ + kt + js * 8);
    }
    __syncthreads();
#pragma unroll
    for (int kk = 0; kk < 2; ++kk) {
      bf16x8 a[4], b[4];
#pragma unroll
      for (int mt = 0; mt < 4; ++mt) {
        int row = wr * 64 + mt * 16 + (l & 15);
        int g = (kk * 4 + (l >> 4)) ^ (row & 7);
        a[mt] = *reinterpret_cast<const bf16x8*>((const char*)As + row * 128 + g * 16);
      }
#pragma unroll
      for (int nt = 0; nt < 4; ++nt) {
        int row = wc * 64 + nt * 16 + (l & 15);
        int g = (kk * 4 + (l >> 4)) ^ (row & 7);
        b[nt] = *reinterpret_cast<const bf16x8*>((const char*)Bs + row * 128 + g * 16);
      }
#pragma unroll
      for (int mt = 0; mt < 4; ++mt)
#pragma unroll
        for (int nt = 0; nt < 4; ++nt)
          acc[mt][nt] = __builtin_amdgcn_mfma_f32_16x16x32_bf16(a[mt], b[nt], acc[mt][nt], 0, 0, 0);
    }
  }
}

// ---------------- QKV GEMM (epilogue scatters to head layout; Q pre-scaled; V transposed) ----------------
__global__ __launch_bounds__(256) void k_gemm_qkv(const __bf16* __restrict__ A,
                                                  const __bf16* __restrict__ Bt,
                                                  __bf16* __restrict__ Qh,
                                                  __bf16* __restrict__ Kh,
                                                  __bf16* __restrict__ VT) {
  __shared__ __bf16 As[128 * 64], Bs[128 * 64];
  f32x4 acc[4][4] = {};
  const int l = threadIdx.x & 63, w = threadIdx.x >> 6, wr = w >> 1, wc = w & 1;
  const int m0 = blockIdx.y * 128, n0 = blockIdx.x * 128;
  gemm_mainloop(A, Bt, m0, n0, As, Bs, acc);
#pragma unroll
  for (int nt = 0; nt < 4; ++nt) {
    int n = n0 + wc * 64 + nt * 16 + (l & 15);
    int sec = n >> 9;           // 0=q 1=k 2=v
    int hh = (n >> 5) & 15;     // head
    int d = n & 31;             // dim in head
#pragma unroll
    for (int mt = 0; mt < 4; ++mt) {
      int m = m0 + wr * 64 + mt * 16 + (l >> 4) * 4;
      int bb = m >> 12, nn = m & 4095;
      size_t bh = (size_t)bb * NHEAD + hh;
      f32x4 v = acc[mt][nt];
      if (sec == 0) {
        __bf16* p = Qh + (bh * NSEQ + nn) * HDIM + d;
        p[0] = (__bf16)(v[0] * C2F); p[HDIM] = (__bf16)(v[1] * C2F);
        p[2 * HDIM] = (__bf16)(v[2] * C2F); p[3 * HDIM] = (__bf16)(v[3] * C2F);
      } else if (sec == 1) {
        __bf16* p = Kh + (bh * NSEQ + nn) * HDIM + d;
        p[0] = (__bf16)v[0]; p[HDIM] = (__bf16)v[1];
        p[2 * HDIM] = (__bf16)v[2]; p[3 * HDIM] = (__bf16)v[3];
      } else {
        bf16x4 o;
        o.x = (__bf16)v[0]; o.y = (__bf16)v[1]; o.z = (__bf16)v[2]; o.w = (__bf16)v[3];
        *reinterpret_cast<bf16x4*>(VT + (bh * HDIM + d) * NSEQ + nn) = o;
      }
    }
  }
}

// ---------------- fused masked attention, v3 ----------------
// 1D grid 1024, 256 thr. XCD-aware decode keeps each bh's K/V on one XCD's L2.
// Swapped QK^T (no cross-lane softmax), no-max exp2 (statically overflow-safe),
// k-permuted PV (P lane-local, V loaded with matching permuted addresses).
// Register double-buffered tiles (named sets, static indices), no LDS/barriers.
struct Tile {
  bf16x8 kf[4];
  bf16x4 vl[2][2], vh[2][2];
  u64 mw0, mw1;
};

__device__ __forceinline__ void load_tile(Tile& T, const __bf16* __restrict__ Kb,
                                          const __bf16* __restrict__ Vb,
                                          const u64* __restrict__ mr0,
                                          const u64* __restrict__ mr1,
                                          int kv, int q16, int g) {
#pragma unroll
  for (int f = 0; f < 4; ++f)
    T.kf[f] = *reinterpret_cast<const bf16x8*>(
        Kb + (size_t)(kv * 64 + f * 16 + q16) * HDIM + g * 8);
#pragma unroll
  for (int jj = 0; jj < 2; ++jj)
#pragma unroll
    for (int dt = 0; dt < 2; ++dt) {
      const __bf16* vr =
          Vb + (size_t)(dt * 16 + q16) * NSEQ + kv * 64 + jj * 32 + g * 4;
      T.vl[jj][dt] = *reinterpret_cast<const bf16x4*>(vr);
      T.vh[jj][dt] = *reinterpret_cast<const bf16x4*>(vr + 16);
    }
  T.mw0 = mr0[kv];
  T.mw1 = mr1[kv];
}

__device__ __forceinline__ void attn_tile(const Tile& T, const bf16x8* qf,
                                          f32x4 acc[2][2], float* lsum, int g) {
#pragma unroll
  for (int rt = 0; rt < 2; ++rt) {
    const u64 mws = (rt ? T.mw1 : T.mw0) >> (4 * g);
    const f32x4 z = {0.f, 0.f, 0.f, 0.f};
    f32x4 s[4];
#pragma unroll
    for (int f = 0; f < 4; ++f)  // S^T: lane holds q=q16, k=16f+4g+r
      s[f] = __builtin_amdgcn_mfma_f32_16x16x32_bf16(T.kf[f], qf[rt], z, 0, 0, 0);

    float p[4][4];
    float ls = 0.f;
#pragma unroll
    for (int f = 0; f < 4; ++f)
#pragma unroll
      for (int r = 0; r < 4; ++r) {
        float pv = __builtin_exp2f(s[f][r]);
        pv = ((mws >> (f * 16 + r)) & 1) ? pv : 0.f;
        p[f][r] = pv;
        ls += pv;
      }
    lsum[rt] += ls;

#pragma unroll
    for (int jj = 0; jj < 2; ++jj) {
      bf16x8 pa;  // natural per-lane k order (matches permuted V)
#pragma unroll
      for (int r = 0; r < 4; ++r) {
        pa[r] = (__bf16)p[2 * jj][r];
        pa[r + 4] = (__bf16)p[2 * jj + 1][r];
      }
#pragma unroll
      for (int dt = 0; dt < 2; ++dt) {
        bf16x8 vb;
#pragma unroll
        for (int e = 0; e < 4; ++e) {
          vb[e] = T.vl[jj][dt][e];
          vb[e + 4] = T.vh[jj][dt][e];
        }
        acc[rt][dt] =
            __builtin_amdgcn_mfma_f32_16x16x32_bf16(pa, vb, acc[rt][dt], 0, 0, 0);
      }
    }
  }
}

__global__ __launch_bounds__(256) void k_attn(const __bf16* __restrict__ Qh,
                                              const __bf16* __restrict__ Kh,
                                              const __bf16* __restrict__ VT,
                                              const u64* __restrict__ mbits,
                                              __bf16* __restrict__ O) {
  const int l = threadIdx.x & 63, w = threadIdx.x >> 6;
  const int g = l >> 4, q16 = l & 15;
  const int bid = blockIdx.x;
  // XCD-aware decode: all 32 q-tiles of one bh share bid%8 (one XCD).
  const int bh = (bid & 7) * 4 + ((bid >> 3) & 3);
  const int qx = bid >> 5;
  const int q0 = qx * 128 + w * 32;
  const __bf16* Qb = Qh + (size_t)bh * NSEQ * HDIM;
  const __bf16* Kb = Kh + (size_t)bh * NSEQ * HDIM;
  const __bf16* Vb = VT + (size_t)bh * HDIM * NSEQ;  // [32][4096]
  const u64* mr0 = mbits + (size_t)(q0 + q16) * 64;
  const u64* mr1 = mbits + (size_t)(q0 + 16 + q16) * 64;

  bf16x8 qf[2];
#pragma unroll
  for (int rt = 0; rt < 2; ++rt)
    qf[rt] = *reinterpret_cast<const bf16x8*>(
        Qb + (size_t)(q0 + rt * 16 + q16) * HDIM + g * 8);

  f32x4 acc[2][2] = {};
  float lsum[2] = {0.f, 0.f};

  Tile Ta, Tb;
  load_tile(Ta, Kb, Vb, mr0, mr1, 0, q16, g);
  for (int kv = 0; kv < 64; kv += 2) {
    load_tile(Tb, Kb, Vb, mr0, mr1, kv + 1, q16, g);
    attn_tile(Ta, qf, acc, lsum, g);
    const int nxt = (kv + 2 < 64) ? kv + 2 : 63;  // last prefetch redundant, harmless
    load_tile(Ta, Kb, Vb, mr0, mr1, nxt, q16, g);
    attn_tile(Tb, qf, acc, lsum, g);
  }

#pragma unroll
  for (int rt = 0; rt < 2; ++rt) {
    lsum[rt] += __shfl_xor(lsum[rt], 16);
    lsum[rt] += __shfl_xor(lsum[rt], 32);
  }

  const int bb = bh >> 4, hh = bh & 15;
#pragma unroll
  for (int rt = 0; rt < 2; ++rt)
#pragma unroll
    for (int r = 0; r < 4; ++r) {
      float inv = 1.f / __shfl(lsum[rt], g * 4 + r);  // row-sum lives at lane q16==g*4+r
      int qrow = q0 + rt * 16 + g * 4 + r;
#pragma unroll
      for (int dt = 0; dt < 2; ++dt)
        O[((size_t)bb * NSEQ + qrow) * DIMQ + hh * HDIM + dt * 16 + q16] =
            (__bf16)(acc[rt][dt][r] * inv);
    }
}

// ---------------- output projection GEMM (fp32 output) ----------------
__global__ __launch_bounds__(256) void k_gemm_proj(const __bf16* __restrict__ A,
                                                   const __bf16* __restrict__ Bt,
                                                   float* __restrict__ Out) {
  __shared__ __bf16 As[128 * 64], Bs[128 * 64];
  f32x4 acc[4][4] = {};
  const int l = threadIdx.x & 63, w = threadIdx.x >> 6, wr = w >> 1, wc = w & 1;
  const int m0 = blockIdx.y * 128, n0 = blockIdx.x * 128;
  gemm_mainloop(A, Bt, m0, n0, As, Bs, acc);
#pragma unroll
  for (int nt = 0; nt < 4; ++nt) {
    int n = n0 + wc * 64 + nt * 16 + (l & 15);
#pragma unroll
    for (int mt = 0; mt < 4; ++mt) {
      int m = m0 + wr * 64 + mt * 16 + (l >> 4) * 4;
      f32x4 v = acc[mt][nt];
      float* p = Out + (size_t)m * DIMQ + n;
      p[0] = v[0]; p[DIMQ] = v[1];
      p[2 * DIMQ] = v[2]; p[3 * DIMQ] = v[3];
    }
  }
}

// ---------------- launcher ----------------
extern "C" void kernel_launch(void* const* d_in, const int* in_sizes, int n_in,
                              void* d_out, int out_size, void* d_ws, size_t ws_size,
                              hipStream_t stream) {
  (void)in_sizes; (void)n_in; (void)out_size; (void)ws_size;
  const float* batch  = (const float*)d_in[0];
  const float* w_qkv  = (const float*)d_in[1];
  const float* w_proj = (const float*)d_in[2];
  const int*   cmask  = (const int*)d_in[3];

  __bf16* Abf = (__bf16*)d_ws;                       // 8192*512 bf16
  __bf16* WqT = Abf + (size_t)8192 * 512;            // 1536*512
  __bf16* WpT = WqT + (size_t)1536 * 512;            // 512*512
  u64*    mb  = (u64*)(WpT + (size_t)512 * 512);     // 4096*64 u64
  __bf16* Qh  = (__bf16*)(mb + (size_t)4096 * 64);   // 32*4096*32
  __bf16* Kh  = Qh + (size_t)32 * NSEQ * HDIM;
  __bf16* VT  = Kh + (size_t)32 * NSEQ * HDIM;
  __bf16* Obf = VT + (size_t)32 * NSEQ * HDIM;       // 8192*512

  k_cvt_bf16<<<4096, 256, 0, stream>>>(batch, Abf);
  k_cvtT<<<dim3(24, 8), 256, 0, stream>>>(w_qkv, WqT, 1536);
  k_cvtT<<<dim3(8, 8), 256, 0, stream>>>(w_proj, WpT, 512);
  k_maskbits<<<4096, 256, 0, stream>>>(cmask, mb);
  k_gemm_qkv<<<dim3(12, 64), 256, 0, stream>>>(Abf, WqT, Qh, Kh, VT);
  k_attn<<<1024, 256, 0, stream>>>(Qh, Kh, VT, mb, Obf);
  k_gemm_proj<<<dim3(4, 64), 256, 0, stream>>>(Obf, WpT, (float*)d_out);
}

// Round 7
// 295.567 us; speedup vs baseline: 1.6111x; 1.4758x over previous
//
#include <hip/hip_runtime.h>
#include <hip/hip_bf16.h>

typedef __attribute__((ext_vector_type(4))) float f32x4;
typedef __attribute__((ext_vector_type(8))) __bf16 bf16x8;
typedef __attribute__((ext_vector_type(4))) __bf16 bf16x4;
typedef unsigned long long u64;

#define DIMQ 512
#define NSEQ 4096
#define NHEAD 16
#define HDIM 32
#define SCALE_QK 0.17677669529663687f
#define C2F (SCALE_QK * 1.4426950408889634f)  // scale * log2(e), folded into Q

__device__ __forceinline__ void gload16(void* lds, const void* g) {
  __builtin_amdgcn_global_load_lds(
      (const __attribute__((address_space(1))) void*)g,
      (__attribute__((address_space(3))) void*)lds, 16, 0, 0);
}

// ---------------- conversion kernels ----------------

__global__ __launch_bounds__(256) void k_cvt_bf16(const float* __restrict__ in,
                                                  __bf16* __restrict__ out) {
  int i = blockIdx.x * 256 + threadIdx.x;
  float4 v = reinterpret_cast<const float4*>(in)[i];
  bf16x4 o;
  o.x = (__bf16)v.x; o.y = (__bf16)v.y; o.z = (__bf16)v.z; o.w = (__bf16)v.w;
  reinterpret_cast<bf16x4*>(out)[i] = o;
}

// in: fp32 [512][Nc]  ->  out: bf16 [Nc][512]  (transpose via LDS tile)
__global__ __launch_bounds__(256) void k_cvtT(const float* __restrict__ in,
                                              __bf16* __restrict__ out, int Nc) {
  __shared__ __bf16 t[64][72];
  int k0 = blockIdx.y * 64, n0 = blockIdx.x * 64;
  int c = threadIdx.x & 63, rr = threadIdx.x >> 6;
#pragma unroll
  for (int i = 0; i < 16; ++i) {
    int r = rr * 16 + i;
    t[r][c] = (__bf16)in[(size_t)(k0 + r) * Nc + n0 + c];
  }
  __syncthreads();
#pragma unroll
  for (int i = 0; i < 16; ++i) {
    int r = rr * 16 + i;
    out[(size_t)(n0 + r) * 512 + k0 + c] = t[c][r];
  }
}

// int32 mask [4096][4096] -> bit mask [4096][64] u64 (bit j of word w = mask[row][w*64+j])
__global__ __launch_bounds__(256) void k_maskbits(const int* __restrict__ mask,
                                                  u64* __restrict__ bits) {
  int row = blockIdx.x;
  int l = threadIdx.x & 63, w = threadIdx.x >> 6;
  const int* mr = mask + (size_t)row * NSEQ;
  for (int t = w; t < 64; t += 4) {
    u64 b = __ballot(mr[t * 64 + l] != 0);
    if (l == 0) bits[(size_t)row * 64 + t] = b;
  }
}

// ---------------- shared GEMM main loop (m97-style, swizzled gload_lds) ----------------
__device__ __forceinline__ void gemm_mainloop(const __bf16* __restrict__ A,
                                              const __bf16* __restrict__ Bt,
                                              int m0, int n0,
                                              __bf16* As, __bf16* Bs,
                                              f32x4 acc[4][4]) {
  const int tid = threadIdx.x, l = tid & 63, w = tid >> 6;
  const int wr = w >> 1, wc = w & 1;
  for (int kt = 0; kt < DIMQ; kt += 64) {
    __syncthreads();
#pragma unroll
    for (int it = 0; it < 4; ++it) {
      int c = it * 256 + tid;
      int row = c >> 3, j = c & 7, js = j ^ (row & 7);
      gload16(As + (size_t)(it * 256 + w * 64) * 8,
              A + (size_t)(m0 + row) * DIMQ + kt + js * 8);
      gload16(Bs + (size_t)(it * 256 + w * 64) * 8,
              Bt + (size_t)(n0 + row) * DIMQ + kt + js * 8);
    }
    __syncthreads();
#pragma unroll
    for (int kk = 0; kk < 2; ++kk) {
      bf16x8 a[4], b[4];
#pragma unroll
      for (int mt = 0; mt < 4; ++mt) {
        int row = wr * 64 + mt * 16 + (l & 15);
        int g = (kk * 4 + (l >> 4)) ^ (row & 7);
        a[mt] = *reinterpret_cast<const bf16x8*>((const char*)As + row * 128 + g * 16);
      }
#pragma unroll
      for (int nt = 0; nt < 4; ++nt) {
        int row = wc * 64 + nt * 16 + (l & 15);
        int g = (kk * 4 + (l >> 4)) ^ (row & 7);
        b[nt] = *reinterpret_cast<const bf16x8*>((const char*)Bs + row * 128 + g * 16);
      }
#pragma unroll
      for (int mt = 0; mt < 4; ++mt)
#pragma unroll
        for (int nt = 0; nt < 4; ++nt)
          acc[mt][nt] = __builtin_amdgcn_mfma_f32_16x16x32_bf16(a[mt], b[nt], acc[mt][nt], 0, 0, 0);
    }
  }
}

// ---------------- QKV GEMM (epilogue scatters to head layout; Q pre-scaled; V transposed) ----------------
__global__ __launch_bounds__(256) void k_gemm_qkv(const __bf16* __restrict__ A,
                                                  const __bf16* __restrict__ Bt,
                                                  __bf16* __restrict__ Qh,
                                                  __bf16* __restrict__ Kh,
                                                  __bf16* __restrict__ VT) {
  __shared__ __bf16 As[128 * 64], Bs[128 * 64];
  f32x4 acc[4][4] = {};
  const int l = threadIdx.x & 63, w = threadIdx.x >> 6, wr = w >> 1, wc = w & 1;
  const int m0 = blockIdx.y * 128, n0 = blockIdx.x * 128;
  gemm_mainloop(A, Bt, m0, n0, As, Bs, acc);
#pragma unroll
  for (int nt = 0; nt < 4; ++nt) {
    int n = n0 + wc * 64 + nt * 16 + (l & 15);
    int sec = n >> 9;           // 0=q 1=k 2=v
    int hh = (n >> 5) & 15;     // head
    int d = n & 31;             // dim in head
#pragma unroll
    for (int mt = 0; mt < 4; ++mt) {
      int m = m0 + wr * 64 + mt * 16 + (l >> 4) * 4;
      int bb = m >> 12, nn = m & 4095;
      size_t bh = (size_t)bb * NHEAD + hh;
      f32x4 v = acc[mt][nt];
      if (sec == 0) {
        __bf16* p = Qh + (bh * NSEQ + nn) * HDIM + d;
        p[0] = (__bf16)(v[0] * C2F); p[HDIM] = (__bf16)(v[1] * C2F);
        p[2 * HDIM] = (__bf16)(v[2] * C2F); p[3 * HDIM] = (__bf16)(v[3] * C2F);
      } else if (sec == 1) {
        __bf16* p = Kh + (bh * NSEQ + nn) * HDIM + d;
        p[0] = (__bf16)v[0]; p[HDIM] = (__bf16)v[1];
        p[2 * HDIM] = (__bf16)v[2]; p[3 * HDIM] = (__bf16)v[3];
      } else {
        bf16x4 o;
        o.x = (__bf16)v[0]; o.y = (__bf16)v[1]; o.z = (__bf16)v[2]; o.w = (__bf16)v[3];
        *reinterpret_cast<bf16x4*>(VT + (bh * HDIM + d) * NSEQ + nn) = o;
      }
    }
  }
}

// ---------------- fused masked attention, v4 ----------------
// 1D grid 1024 (XCD-aware decode), 256 thr = 4 waves sharing LDS-staged K/V.
// K tile [64][32] bf16 (slots XOR (row>>1)&3), V tile [32][64] bf16 (16B granules
// XOR row&7); both staged with global_load_lds (linear dest, pre-swizzled source).
// Swapped QK^T, no-max exp2 softmax, k-permuted PV, row-sums via MFMA vs ones.
__device__ __forceinline__ void attn_compute(const __bf16* __restrict__ Kl,
                                             const __bf16* __restrict__ Vl,
                                             const bf16x8 qf[2], u64 mw0, u64 mw1,
                                             f32x4 acc[2][2], f32x4 accS[2],
                                             int kOff, const int vA[4],
                                             bf16x8 ones, int g) {
  bf16x8 kf[4];
#pragma unroll
  for (int f = 0; f < 4; ++f)
    kf[f] = *reinterpret_cast<const bf16x8*>(Kl + kOff + f * 512);

  bf16x4 vv[2][2][2];  // [jj][hi][dt]
#pragma unroll
  for (int jj = 0; jj < 2; ++jj)
#pragma unroll
    for (int hi = 0; hi < 2; ++hi)
#pragma unroll
      for (int dt = 0; dt < 2; ++dt)
        vv[jj][hi][dt] =
            *reinterpret_cast<const bf16x4*>(Vl + vA[jj * 2 + hi] + dt * 1024);

#pragma unroll
  for (int rt = 0; rt < 2; ++rt) {
    const u64 mws = (rt ? mw1 : mw0) >> (4 * g);
    const f32x4 z = {0.f, 0.f, 0.f, 0.f};
    f32x4 s[4];
#pragma unroll
    for (int f = 0; f < 4; ++f)  // S^T: lane holds q=q16, k=16f+4g+r
      s[f] = __builtin_amdgcn_mfma_f32_16x16x32_bf16(kf[f], qf[rt], z, 0, 0, 0);

    float p[4][4];
#pragma unroll
    for (int f = 0; f < 4; ++f)
#pragma unroll
      for (int r = 0; r < 4; ++r) {
        float pv = __builtin_exp2f(s[f][r]);
        p[f][r] = ((mws >> (f * 16 + r)) & 1) ? pv : 0.f;
      }

#pragma unroll
    for (int jj = 0; jj < 2; ++jj) {
      bf16x8 pa;  // per-lane k order (matches permuted V)
#pragma unroll
      for (int r = 0; r < 4; ++r) {
        pa[r] = (__bf16)p[2 * jj][r];
        pa[r + 4] = (__bf16)p[2 * jj + 1][r];
      }
      accS[rt] = __builtin_amdgcn_mfma_f32_16x16x32_bf16(pa, ones, accS[rt], 0, 0, 0);
#pragma unroll
      for (int dt = 0; dt < 2; ++dt) {
        bf16x8 vb;
#pragma unroll
        for (int e = 0; e < 4; ++e) {
          vb[e] = vv[jj][0][dt][e];
          vb[e + 4] = vv[jj][1][dt][e];
        }
        acc[rt][dt] =
            __builtin_amdgcn_mfma_f32_16x16x32_bf16(pa, vb, acc[rt][dt], 0, 0, 0);
      }
    }
  }
}

__global__ __launch_bounds__(256) void k_attn(const __bf16* __restrict__ Qh,
                                              const __bf16* __restrict__ Kh,
                                              const __bf16* __restrict__ VT,
                                              const u64* __restrict__ mbits,
                                              __bf16* __restrict__ O) {
  __shared__ __bf16 Klds[2][2048];  // [64 rows][4 slots x 16B], slot-swizzled
  __shared__ __bf16 Vlds[2][2048];  // [32 rows][8 granules x 16B], granule-swizzled
  const int tid = threadIdx.x;
  const int l = tid & 63, w = tid >> 6;
  const int g = l >> 4, q16 = l & 15;
  const int bid = blockIdx.x;
  const int bh = (bid & 7) * 4 + ((bid >> 3) & 3);  // XCD-aware decode
  const int qx = bid >> 5;
  const int q0 = qx * 128 + w * 32;
  const __bf16* Qb = Qh + (size_t)bh * NSEQ * HDIM;
  const __bf16* Kb = Kh + (size_t)bh * NSEQ * HDIM;
  const __bf16* Vb = VT + (size_t)bh * HDIM * NSEQ;  // [32][4096]
  const u64* mr0 = mbits + (size_t)(q0 + q16) * 64;
  const u64* mr1 = mbits + (size_t)(q0 + 16 + q16) * 64;

  // staging sources (pre-swizzled so linear LDS dest + swizzled read match)
  const int rk = tid >> 2, gsK = (tid & 3) ^ ((rk >> 1) & 3);
  const __bf16* srcK = Kb + (size_t)rk * HDIM + gsK * 8;   // += t*2048
  const int rv = tid >> 3, gV = (tid & 7) ^ (rv & 7);
  const __bf16* srcV = Vb + (size_t)rv * NSEQ + gV * 8;    // += t*64

  // LDS read addresses (loop-invariant)
  const int kOff = q16 * 32 + (g ^ ((q16 >> 1) & 3)) * 8;
  int vA[4];
#pragma unroll
  for (int jj = 0; jj < 2; ++jj)
#pragma unroll
    for (int hi = 0; hi < 2; ++hi)
      vA[jj * 2 + hi] =
          q16 * 64 + (((jj * 4 + hi * 2 + (g >> 1)) ^ (q16 & 7)) * 8) + (g & 1) * 4;

  bf16x8 qf[2];
#pragma unroll
  for (int rt = 0; rt < 2; ++rt)
    qf[rt] = *reinterpret_cast<const bf16x8*>(
        Qb + (size_t)(q0 + rt * 16 + q16) * HDIM + g * 8);

  bf16x8 ones;
#pragma unroll
  for (int e = 0; e < 8; ++e) ones[e] = (__bf16)1.0f;

  f32x4 acc[2][2] = {};
  f32x4 accS[2] = {};

  // prologue: stage tile 0 into buf0, prefetch its mask words
  gload16(&Klds[0][0] + tid * 8, srcK);
  gload16(&Vlds[0][0] + tid * 8, srcV);
  u64 a0 = mr0[0], a1 = mr1[0];
  u64 b0, b1;
  __syncthreads();

  for (int t = 0; t < 64; t += 2) {
    // phase A: stage tile t+1 -> buf1, compute tile t from buf0
    gload16(&Klds[1][0] + tid * 8, srcK + (size_t)(t + 1) * 2048);
    gload16(&Vlds[1][0] + tid * 8, srcV + (size_t)(t + 1) * 64);
    b0 = mr0[t + 1]; b1 = mr1[t + 1];
    attn_compute(&Klds[0][0], &Vlds[0][0], qf, a0, a1, acc, accS, kOff, vA, ones, g);
    __syncthreads();
    // phase B: stage tile t+2 -> buf0 (clamped), compute tile t+1 from buf1
    const int t2 = (t + 2 < 64) ? t + 2 : 63;
    gload16(&Klds[0][0] + tid * 8, srcK + (size_t)t2 * 2048);
    gload16(&Vlds[0][0] + tid * 8, srcV + (size_t)t2 * 64);
    a0 = mr0[t2]; a1 = mr1[t2];
    attn_compute(&Klds[1][0], &Vlds[1][0], qf, b0, b1, acc, accS, kOff, vA, ones, g);
    __syncthreads();
  }

  const int bb = bh >> 4, hh = bh & 15;
#pragma unroll
  for (int rt = 0; rt < 2; ++rt)
#pragma unroll
    for (int r = 0; r < 4; ++r) {
      float inv = 1.f / accS[rt][r];  // denominator lands in the same lane/reg
      int qrow = q0 + rt * 16 + g * 4 + r;
#pragma unroll
      for (int dt = 0; dt < 2; ++dt)
        O[((size_t)bb * NSEQ + qrow) * DIMQ + hh * HDIM + dt * 16 + q16] =
            (__bf16)(acc[rt][dt][r] * inv);
    }
}

// ---------------- output projection GEMM (fp32 output) ----------------
__global__ __launch_bounds__(256) void k_gemm_proj(const __bf16* __restrict__ A,
                                                   const __bf16* __restrict__ Bt,
                                                   float* __restrict__ Out) {
  __shared__ __bf16 As[128 * 64], Bs[128 * 64];
  f32x4 acc[4][4] = {};
  const int l = threadIdx.x & 63, w = threadIdx.x >> 6, wr = w >> 1, wc = w & 1;
  const int m0 = blockIdx.y * 128, n0 = blockIdx.x * 128;
  gemm_mainloop(A, Bt, m0, n0, As, Bs, acc);
#pragma unroll
  for (int nt = 0; nt < 4; ++nt) {
    int n = n0 + wc * 64 + nt * 16 + (l & 15);
#pragma unroll
    for (int mt = 0; mt < 4; ++mt) {
      int m = m0 + wr * 64 + mt * 16 + (l >> 4) * 4;
      f32x4 v = acc[mt][nt];
      float* p = Out + (size_t)m * DIMQ + n;
      p[0] = v[0]; p[DIMQ] = v[1];
      p[2 * DIMQ] = v[2]; p[3 * DIMQ] = v[3];
    }
  }
}

// ---------------- launcher ----------------
extern "C" void kernel_launch(void* const* d_in, const int* in_sizes, int n_in,
                              void* d_out, int out_size, void* d_ws, size_t ws_size,
                              hipStream_t stream) {
  (void)in_sizes; (void)n_in; (void)out_size; (void)ws_size;
  const float* batch  = (const float*)d_in[0];
  const float* w_qkv  = (const float*)d_in[1];
  const float* w_proj = (const float*)d_in[2];
  const int*   cmask  = (const int*)d_in[3];

  __bf16* Abf = (__bf16*)d_ws;                       // 8192*512 bf16
  __bf16* WqT = Abf + (size_t)8192 * 512;            // 1536*512
  __bf16* WpT = WqT + (size_t)1536 * 512;            // 512*512
  u64*    mb  = (u64*)(WpT + (size_t)512 * 512);     // 4096*64 u64
  __bf16* Qh  = (__bf16*)(mb + (size_t)4096 * 64);   // 32*4096*32
  __bf16* Kh  = Qh + (size_t)32 * NSEQ * HDIM;
  __bf16* VT  = Kh + (size_t)32 * NSEQ * HDIM;
  __bf16* Obf = VT + (size_t)32 * NSEQ * HDIM;       // 8192*512

  k_cvt_bf16<<<4096, 256, 0, stream>>>(batch, Abf);
  k_cvtT<<<dim3(24, 8), 256, 0, stream>>>(w_qkv, WqT, 1536);
  k_cvtT<<<dim3(8, 8), 256, 0, stream>>>(w_proj, WpT, 512);
  k_maskbits<<<4096, 256, 0, stream>>>(cmask, mb);
  k_gemm_qkv<<<dim3(12, 64), 256, 0, stream>>>(Abf, WqT, Qh, Kh, VT);
  k_attn<<<1024, 256, 0, stream>>>(Qh, Kh, VT, mb, Obf);
  k_gemm_proj<<<dim3(4, 64), 256, 0, stream>>>(Obf, WpT, (float*)d_out);
}

// Round 8
// 279.268 us; speedup vs baseline: 1.7052x; 1.0584x over previous
//
#include <hip/hip_runtime.h>
#include <hip/hip_bf16.h>

typedef __attribute__((ext_vector_type(4))) float f32x4;
typedef __attribute__((ext_vector_type(8))) __bf16 bf16x8;
typedef __attribute__((ext_vector_type(4))) __bf16 bf16x4;
typedef unsigned long long u64;

#define DIMQ 512
#define NSEQ 4096
#define NHEAD 16
#define HDIM 32
#define SCALE_QK 0.17677669529663687f
#define C2F (SCALE_QK * 1.4426950408889634f)  // scale * log2(e), folded into Q

__device__ __forceinline__ void gload16(void* lds, const void* g) {
  __builtin_amdgcn_global_load_lds(
      (const __attribute__((address_space(1))) void*)g,
      (__attribute__((address_space(3))) void*)lds, 16, 0, 0);
}

// ---------------- conversion kernels ----------------

__global__ __launch_bounds__(256) void k_cvt_bf16(const float* __restrict__ in,
                                                  __bf16* __restrict__ out) {
  int i = blockIdx.x * 256 + threadIdx.x;
  float4 v = reinterpret_cast<const float4*>(in)[i];
  bf16x4 o;
  o.x = (__bf16)v.x; o.y = (__bf16)v.y; o.z = (__bf16)v.z; o.w = (__bf16)v.w;
  reinterpret_cast<bf16x4*>(out)[i] = o;
}

// in: fp32 [512][Nc]  ->  out: bf16 [Nc][512]  (transpose via LDS tile)
__global__ __launch_bounds__(256) void k_cvtT(const float* __restrict__ in,
                                              __bf16* __restrict__ out, int Nc) {
  __shared__ __bf16 t[64][72];
  int k0 = blockIdx.y * 64, n0 = blockIdx.x * 64;
  int c = threadIdx.x & 63, rr = threadIdx.x >> 6;
#pragma unroll
  for (int i = 0; i < 16; ++i) {
    int r = rr * 16 + i;
    t[r][c] = (__bf16)in[(size_t)(k0 + r) * Nc + n0 + c];
  }
  __syncthreads();
#pragma unroll
  for (int i = 0; i < 16; ++i) {
    int r = rr * 16 + i;
    out[(size_t)(n0 + r) * 512 + k0 + c] = t[c][r];
  }
}

// int32 mask [4096][4096] -> bit mask [4096][64] u64 (bit j of word w = mask[row][w*64+j])
__global__ __launch_bounds__(256) void k_maskbits(const int* __restrict__ mask,
                                                  u64* __restrict__ bits) {
  int row = blockIdx.x;
  int l = threadIdx.x & 63, w = threadIdx.x >> 6;
  const int* mr = mask + (size_t)row * NSEQ;
  for (int t = w; t < 64; t += 4) {
    u64 b = __ballot(mr[t * 64 + l] != 0);
    if (l == 0) bits[(size_t)row * 64 + t] = b;
  }
}

// ---------------- shared GEMM main loop (m97-style, swizzled gload_lds) ----------------
__device__ __forceinline__ void gemm_mainloop(const __bf16* __restrict__ A,
                                              const __bf16* __restrict__ Bt,
                                              int m0, int n0,
                                              __bf16* As, __bf16* Bs,
                                              f32x4 acc[4][4]) {
  const int tid = threadIdx.x, l = tid & 63, w = tid >> 6;
  const int wr = w >> 1, wc = w & 1;
  for (int kt = 0; kt < DIMQ; kt += 64) {
    __syncthreads();
#pragma unroll
    for (int it = 0; it < 4; ++it) {
      int c = it * 256 + tid;
      int row = c >> 3, j = c & 7, js = j ^ (row & 7);
      gload16(As + (size_t)(it * 256 + w * 64) * 8,
              A + (size_t)(m0 + row) * DIMQ + kt + js * 8);
      gload16(Bs + (size_t)(it * 256 + w * 64) * 8,
              Bt + (size_t)(n0 + row) * DIMQ + kt + js * 8);
    }
    __syncthreads();
#pragma unroll
    for (int kk = 0; kk < 2; ++kk) {
      bf16x8 a[4], b[4];
#pragma unroll
      for (int mt = 0; mt < 4; ++mt) {
        int row = wr * 64 + mt * 16 + (l & 15);
        int g = (kk * 4 + (l >> 4)) ^ (row & 7);
        a[mt] = *reinterpret_cast<const bf16x8*>((const char*)As + row * 128 + g * 16);
      }
#pragma unroll
      for (int nt = 0; nt < 4; ++nt) {
        int row = wc * 64 + nt * 16 + (l & 15);
        int g = (kk * 4 + (l >> 4)) ^ (row & 7);
        b[nt] = *reinterpret_cast<const bf16x8*>((const char*)Bs + row * 128 + g * 16);
      }
#pragma unroll
      for (int mt = 0; mt < 4; ++mt)
#pragma unroll
        for (int nt = 0; nt < 4; ++nt)
          acc[mt][nt] = __builtin_amdgcn_mfma_f32_16x16x32_bf16(a[mt], b[nt], acc[mt][nt], 0, 0, 0);
    }
  }
}

// ---------------- QKV GEMM (epilogue: head layout; Q pre-scaled; V transposed + k-permuted) ----------------
__global__ __launch_bounds__(256) void k_gemm_qkv(const __bf16* __restrict__ A,
                                                  const __bf16* __restrict__ Bt,
                                                  __bf16* __restrict__ Qh,
                                                  __bf16* __restrict__ Kh,
                                                  __bf16* __restrict__ VT) {
  __shared__ __bf16 As[128 * 64], Bs[128 * 64];
  f32x4 acc[4][4] = {};
  const int l = threadIdx.x & 63, w = threadIdx.x >> 6, wr = w >> 1, wc = w & 1;
  const int m0 = blockIdx.y * 128, n0 = blockIdx.x * 128;
  gemm_mainloop(A, Bt, m0, n0, As, Bs, acc);
#pragma unroll
  for (int nt = 0; nt < 4; ++nt) {
    int n = n0 + wc * 64 + nt * 16 + (l & 15);
    int sec = n >> 9;           // 0=q 1=k 2=v
    int hh = (n >> 5) & 15;     // head
    int d = n & 31;             // dim in head
#pragma unroll
    for (int mt = 0; mt < 4; ++mt) {
      int m = m0 + wr * 64 + mt * 16 + (l >> 4) * 4;
      int bb = m >> 12, nn = m & 4095;
      size_t bh = (size_t)bb * NHEAD + hh;
      f32x4 v = acc[mt][nt];
      if (sec == 0) {
        __bf16* p = Qh + (bh * NSEQ + nn) * HDIM + d;
        p[0] = (__bf16)(v[0] * C2F); p[HDIM] = (__bf16)(v[1] * C2F);
        p[2 * HDIM] = (__bf16)(v[2] * C2F); p[3 * HDIM] = (__bf16)(v[3] * C2F);
      } else if (sec == 1) {
        __bf16* p = Kh + (bh * NSEQ + nn) * HDIM + d;
        p[0] = (__bf16)v[0]; p[HDIM] = (__bf16)v[1];
        p[2 * HDIM] = (__bf16)v[2]; p[3 * HDIM] = (__bf16)v[3];
      } else {
        // k-permuted V: within each 32-kv group, low5 = hi*16 + g*4 + r -> g*8 + hi*4 + r
        // (nn % 4 == 0, so r = 0 for the vector base)
        int low = nn & 31;
        int nnp = (nn & ~31) | (((low >> 2) & 3) << 3) | (((low >> 4) & 1) << 2);
        bf16x4 o;
        o.x = (__bf16)v[0]; o.y = (__bf16)v[1]; o.z = (__bf16)v[2]; o.w = (__bf16)v[3];
        *reinterpret_cast<bf16x4*>(VT + (bh * HDIM + d) * NSEQ + nnp) = o;
      }
    }
  }
}

// ---------------- fused masked attention, v5 ----------------
// grid 2048 (XCD-aware decode), 256 thr = 4 waves; wave owns 16 q-rows.
// K tile [64][32] (slot XOR (row>>1)&3); V tile [32 d][64 kp] with global k-perm
// so PV B-frag = single ds_read_b128 (granule XOR d&7, pre-applied at source).
// Swapped QK^T, no-max exp2, row-sums via MFMA vs ones. Double-buffered LDS.
__device__ __forceinline__ void attn_compute(const __bf16* __restrict__ Kl,
                                             const __bf16* __restrict__ Vl,
                                             bf16x8 qf, u64 mw,
                                             f32x4 acc[2], f32x4& accS,
                                             int kOff, const int vOff[2][2],
                                             bf16x8 ones, int g) {
  bf16x8 kf[4];
#pragma unroll
  for (int f = 0; f < 4; ++f)
    kf[f] = *reinterpret_cast<const bf16x8*>(Kl + kOff + f * 512);

  bf16x8 vvb[2][2];  // [jj][dt], single b128 each
#pragma unroll
  for (int jj = 0; jj < 2; ++jj)
#pragma unroll
    for (int dt = 0; dt < 2; ++dt)
      vvb[jj][dt] = *reinterpret_cast<const bf16x8*>(Vl + vOff[jj][dt]);

  const u64 mws = mw >> (4 * g);
  const f32x4 z = {0.f, 0.f, 0.f, 0.f};
  f32x4 s[4];
#pragma unroll
  for (int f = 0; f < 4; ++f)  // S^T: lane holds q=q16, k=16f+4g+r
    s[f] = __builtin_amdgcn_mfma_f32_16x16x32_bf16(kf[f], qf, z, 0, 0, 0);

  float p[4][4];
#pragma unroll
  for (int f = 0; f < 4; ++f)
#pragma unroll
    for (int r = 0; r < 4; ++r) {
      float pv = __builtin_exp2f(s[f][r]);
      p[f][r] = ((mws >> (f * 16 + r)) & 1) ? pv : 0.f;
    }

#pragma unroll
  for (int jj = 0; jj < 2; ++jj) {
    bf16x8 pa;  // k order e = hi*4 + r matches permuted-V b128 order
#pragma unroll
    for (int r = 0; r < 4; ++r) {
      pa[r] = (__bf16)p[2 * jj][r];
      pa[r + 4] = (__bf16)p[2 * jj + 1][r];
    }
    accS = __builtin_amdgcn_mfma_f32_16x16x32_bf16(pa, ones, accS, 0, 0, 0);
#pragma unroll
    for (int dt = 0; dt < 2; ++dt)
      acc[dt] = __builtin_amdgcn_mfma_f32_16x16x32_bf16(pa, vvb[jj][dt], acc[dt], 0, 0, 0);
  }
}

__global__ __launch_bounds__(256, 8) void k_attn(const __bf16* __restrict__ Qh,
                                                 const __bf16* __restrict__ Kh,
                                                 const __bf16* __restrict__ VT,
                                                 const u64* __restrict__ mbits,
                                                 __bf16* __restrict__ O) {
  __shared__ __bf16 Klds[2][2048];  // [64 rows][4 slots x 16B], slot-swizzled
  __shared__ __bf16 Vlds[2][2048];  // [32 d][8 granules x 16B], granule-swizzled
  const int tid = threadIdx.x;
  const int l = tid & 63, w = tid >> 6;
  const int g = l >> 4, q16 = l & 15;
  const int bid = blockIdx.x;
  const int bh = (bid & 7) * 4 + ((bid >> 3) & 3);  // XCD-aware decode
  const int qx = bid >> 5;                          // 0..63
  const int q0 = qx * 64 + w * 16;
  const __bf16* Qb = Qh + (size_t)bh * NSEQ * HDIM;
  const __bf16* Kb = Kh + (size_t)bh * NSEQ * HDIM;
  const __bf16* Vb = VT + (size_t)bh * HDIM * NSEQ;  // [32 d][4096 kp]
  const u64* mr = mbits + (size_t)(q0 + q16) * 64;

  // staging sources (pre-swizzled: linear LDS dest + swizzled read match)
  const int rk = tid >> 2, gsK = (tid & 3) ^ ((rk >> 1) & 3);
  const __bf16* srcK = Kb + (size_t)rk * HDIM + gsK * 8;   // += t*2048
  const int dv = tid >> 3, gv = (tid & 7) ^ (dv & 7);
  const __bf16* srcV = Vb + (size_t)dv * NSEQ + gv * 8;    // += t*64

  // LDS read offsets (loop-invariant, elements)
  const int kOff = q16 * 32 + (g ^ ((q16 >> 1) & 3)) * 8;
  int vOff[2][2];
#pragma unroll
  for (int jj = 0; jj < 2; ++jj)
#pragma unroll
    for (int dt = 0; dt < 2; ++dt) {
      int d = dt * 16 + q16;
      vOff[jj][dt] = d * 64 + ((4 * jj + g) ^ (d & 7)) * 8;
    }

  bf16x8 qf = *reinterpret_cast<const bf16x8*>(
      Qb + (size_t)(q0 + q16) * HDIM + g * 8);

  bf16x8 ones;
#pragma unroll
  for (int e = 0; e < 8; ++e) ones[e] = (__bf16)1.0f;

  f32x4 acc[2] = {};
  f32x4 accS = {};

  // prologue: stage tile 0 into buf0
  gload16(&Klds[0][0] + tid * 8, srcK);
  gload16(&Vlds[0][0] + tid * 8, srcV);
  u64 a0 = mr[0], b0;
  __syncthreads();

  for (int t = 0; t < 64; t += 2) {
    // phase A: stage t+1 -> buf1, compute t from buf0
    gload16(&Klds[1][0] + tid * 8, srcK + (size_t)(t + 1) * 2048);
    gload16(&Vlds[1][0] + tid * 8, srcV + (size_t)(t + 1) * 64);
    b0 = mr[t + 1];
    attn_compute(&Klds[0][0], &Vlds[0][0], qf, a0, acc, accS, kOff, vOff, ones, g);
    __syncthreads();
    // phase B: stage t+2 -> buf0 (clamped), compute t+1 from buf1
    const int t2 = (t + 2 < 64) ? t + 2 : 63;
    gload16(&Klds[0][0] + tid * 8, srcK + (size_t)t2 * 2048);
    gload16(&Vlds[0][0] + tid * 8, srcV + (size_t)t2 * 64);
    a0 = mr[t2];
    attn_compute(&Klds[1][0], &Vlds[1][0], qf, b0, acc, accS, kOff, vOff, ones, g);
    __syncthreads();
  }

  const int bb = bh >> 4, hh = bh & 15;
#pragma unroll
  for (int r = 0; r < 4; ++r) {
    float inv = 1.f / accS[r];  // denominator in the same lane/reg as numerator
    int qrow = q0 + g * 4 + r;
#pragma unroll
    for (int dt = 0; dt < 2; ++dt)
      O[((size_t)bb * NSEQ + qrow) * DIMQ + hh * HDIM + dt * 16 + q16] =
          (__bf16)(acc[dt][r] * inv);
  }
}

// ---------------- output projection GEMM (fp32 output) ----------------
__global__ __launch_bounds__(256) void k_gemm_proj(const __bf16* __restrict__ A,
                                                   const __bf16* __restrict__ Bt,
                                                   float* __restrict__ Out) {
  __shared__ __bf16 As[128 * 64], Bs[128 * 64];
  f32x4 acc[4][4] = {};
  const int l = threadIdx.x & 63, w = threadIdx.x >> 6, wr = w >> 1, wc = w & 1;
  const int m0 = blockIdx.y * 128, n0 = blockIdx.x * 128;
  gemm_mainloop(A, Bt, m0, n0, As, Bs, acc);
#pragma unroll
  for (int nt = 0; nt < 4; ++nt) {
    int n = n0 + wc * 64 + nt * 16 + (l & 15);
#pragma unroll
    for (int mt = 0; mt < 4; ++mt) {
      int m = m0 + wr * 64 + mt * 16 + (l >> 4) * 4;
      f32x4 v = acc[mt][nt];
      float* p = Out + (size_t)m * DIMQ + n;
      p[0] = v[0]; p[DIMQ] = v[1];
      p[2 * DIMQ] = v[2]; p[3 * DIMQ] = v[3];
    }
  }
}

// ---------------- launcher ----------------
extern "C" void kernel_launch(void* const* d_in, const int* in_sizes, int n_in,
                              void* d_out, int out_size, void* d_ws, size_t ws_size,
                              hipStream_t stream) {
  (void)in_sizes; (void)n_in; (void)out_size; (void)ws_size;
  const float* batch  = (const float*)d_in[0];
  const float* w_qkv  = (const float*)d_in[1];
  const float* w_proj = (const float*)d_in[2];
  const int*   cmask  = (const int*)d_in[3];

  __bf16* Abf = (__bf16*)d_ws;                       // 8192*512 bf16
  __bf16* WqT = Abf + (size_t)8192 * 512;            // 1536*512
  __bf16* WpT = WqT + (size_t)1536 * 512;            // 512*512
  u64*    mb  = (u64*)(WpT + (size_t)512 * 512);     // 4096*64 u64
  __bf16* Qh  = (__bf16*)(mb + (size_t)4096 * 64);   // 32*4096*32
  __bf16* Kh  = Qh + (size_t)32 * NSEQ * HDIM;
  __bf16* VT  = Kh + (size_t)32 * NSEQ * HDIM;
  __bf16* Obf = VT + (size_t)32 * NSEQ * HDIM;       // 8192*512

  k_cvt_bf16<<<4096, 256, 0, stream>>>(batch, Abf);
  k_cvtT<<<dim3(24, 8), 256, 0, stream>>>(w_qkv, WqT, 1536);
  k_cvtT<<<dim3(8, 8), 256, 0, stream>>>(w_proj, WpT, 512);
  k_maskbits<<<4096, 256, 0, stream>>>(cmask, mb);
  k_gemm_qkv<<<dim3(12, 64), 256, 0, stream>>>(Abf, WqT, Qh, Kh, VT);
  k_attn<<<2048, 256, 0, stream>>>(Qh, Kh, VT, mb, Obf);
  k_gemm_proj<<<dim3(4, 64), 256, 0, stream>>>(Obf, WpT, (float*)d_out);
}